// Round 5
// baseline (276.873 us; speedup 1.0000x reference)
//
#include <hip/hip_runtime.h>
#include <hip/hip_bf16.h>

typedef unsigned short u16;
typedef __attribute__((ext_vector_type(8))) short short8;
typedef __attribute__((ext_vector_type(4))) float f32x4;
typedef __attribute__((ext_vector_type(4))) unsigned short u16x4;

#define SEQ 2048
#define NH 16
#define HD 64
#define DM 1024
#define LN_DECAY (-0.051293294387550536f)

__device__ __forceinline__ float b2f(u16 u) {
    return __uint_as_float(((unsigned int)u) << 16);
}
__device__ __forceinline__ u16 f2b(float f) {
    unsigned int u = __float_as_uint(f);
    u += 0x7fffu + ((u >> 16) & 1u);   // round-to-nearest-even
    return (u16)(u >> 16);
}
__device__ __forceinline__ f32x4 mfma16(short8 a, short8 b, f32x4 c) {
    return __builtin_amdgcn_mfma_f32_16x16x32_bf16(a, b, c, 0, 0, 0);
}

// ---------------- dtype detection ----------------
__global__ __launch_bounds__(64) void detect_dtype(const u16* __restrict__ W,
                                                   int* __restrict__ flag) {
    int t = threadIdx.x;
    int hit = 0;
    for (int i = t; i < 512; i += 64) {
        u16 u = W[2 * i];
        int e = (u >> 7) & 0xFF;
        if (e >= 0xC0) hit = 1;
    }
    unsigned long long m = __ballot(hit);
    if (t == 0) *flag = (m != 0ULL) ? 1 : 0;
}

// ---------------- input canonicalization to bf16 ----------------
__global__ __launch_bounds__(256) void convert_x(const void* __restrict__ x,
                                                 const int* __restrict__ flag,
                                                 u16* __restrict__ xc) {
    int i = (blockIdx.x * 256 + threadIdx.x) * 4;
    if (*flag) {
        f32x4 v = *(const f32x4*)((const float*)x + i);
        u16x4 o = { f2b(v[0]), f2b(v[1]), f2b(v[2]), f2b(v[3]) };
        *(u16x4*)(xc + i) = o;
    } else {
        *(u16x4*)(xc + i) = *(const u16x4*)((const u16*)x + i);
    }
}

__global__ __launch_bounds__(256) void convert_small(
    const void* __restrict__ p0, const void* __restrict__ p1,
    const void* __restrict__ p2, const void* __restrict__ p3,
    const void* __restrict__ p4, const void* __restrict__ p5,
    const int* __restrict__ flag,
    u16* __restrict__ o0, u16* __restrict__ o1, u16* __restrict__ o2,
    u16* __restrict__ o3, u16* __restrict__ o4, u16* __restrict__ o5) {
    const void* in; u16* out;
    switch (blockIdx.x) {
        case 0: in = p0; out = o0; break;
        case 1: in = p1; out = o1; break;
        case 2: in = p2; out = o2; break;
        case 3: in = p3; out = o3; break;
        case 4: in = p4; out = o4; break;
        default: in = p5; out = o5; break;
    }
    int i = threadIdx.x * 4;
    if (*flag) {
        f32x4 v = *(const f32x4*)((const float*)in + i);
        u16x4 o = { f2b(v[0]), f2b(v[1]), f2b(v[2]), f2b(v[3]) };
        *(u16x4*)(out + i) = o;
    } else {
        *(u16x4*)(out + i) = *(const u16x4*)((const u16*)in + i);
    }
}

// ---------------- weight transpose+convert: W[k][n] -> WT[n][k] bf16 -------
__global__ __launch_bounds__(256) void transpose4(
    const void* __restrict__ W0, const void* __restrict__ W1,
    const void* __restrict__ W2, const void* __restrict__ W3,
    const int* __restrict__ flag,
    u16* __restrict__ T0, u16* __restrict__ T1,
    u16* __restrict__ T2, u16* __restrict__ T3)
{
    __shared__ u16 tile[32][33];
    const void* W; u16* T;
    int z = blockIdx.z;
    if (z == 0)      { W = W0; T = T0; }
    else if (z == 1) { W = W1; T = T1; }
    else if (z == 2) { W = W2; T = T2; }
    else             { W = W3; T = T3; }
    int fl = *flag;
    int t = threadIdx.x;
    int r = t >> 5, c = t & 31;
    int bn = blockIdx.x * 32, bk = blockIdx.y * 32;
#pragma unroll
    for (int i = 0; i < 4; i++) {
        size_t idx = (size_t)(bk + r + i*8) * DM + bn + c;
        tile[r + i*8][c] = fl ? f2b(((const float*)W)[idx]) : ((const u16*)W)[idx];
    }
    __syncthreads();
#pragma unroll
    for (int i = 0; i < 4; i++)
        T[(size_t)(bn + r + i*8) * DM + bk + c] = tile[c][r + i*8];
}

// ---------------- 128x128 MFMA GEMM body ----------------
__device__ __forceinline__ void gemm_body(
    const u16* __restrict__ A, const u16* __restrict__ BT,
    const u16* __restrict__ bias, u16* __restrict__ outB,
    float* __restrict__ outF, int mode,
    int m0, int n0, int t)
{
    __shared__ u16 As[128][40];
    __shared__ u16 Bs[128][40];
    int w = t >> 6, l = t & 63;
    int lane16 = l & 15, quad = l >> 4;
    int wm = (w >> 1) * 64, wn = (w & 1) * 64;
    int lr = t >> 2, lu = t & 3;

    f32x4 zero = {0.f, 0.f, 0.f, 0.f};
    f32x4 acc[4][4];
#pragma unroll
    for (int i = 0; i < 4; i++)
#pragma unroll
        for (int j = 0; j < 4; j++)
            acc[i][j] = zero;

    for (int k0 = 0; k0 < DM; k0 += 32) {
        __syncthreads();
        *(short8*)(&As[lr][lu*8])      = *(const short8*)(A  + (size_t)(m0+lr)   *DM + k0 + lu*8);
        *(short8*)(&As[lr+64][lu*8])   = *(const short8*)(A  + (size_t)(m0+lr+64)*DM + k0 + lu*8);
        *(short8*)(&Bs[lr][lu*8])      = *(const short8*)(BT + (size_t)(n0+lr)   *DM + k0 + lu*8);
        *(short8*)(&Bs[lr+64][lu*8])   = *(const short8*)(BT + (size_t)(n0+lr+64)*DM + k0 + lu*8);
        __syncthreads();
        short8 af[4], bf[4];
#pragma unroll
        for (int i = 0; i < 4; i++) {
            af[i] = *(const short8*)(&As[wm + i*16 + lane16][quad*8]);
            bf[i] = *(const short8*)(&Bs[wn + i*16 + lane16][quad*8]);
        }
#pragma unroll
        for (int i = 0; i < 4; i++)
#pragma unroll
            for (int j = 0; j < 4; j++)
                acc[i][j] = mfma16(af[i], bf[j], acc[i][j]);
    }

#pragma unroll
    for (int i = 0; i < 4; i++) {
#pragma unroll
        for (int j = 0; j < 4; j++) {
            int n = n0 + wn + j*16 + lane16;
            float bv = b2f(bias[n]);
#pragma unroll
            for (int r = 0; r < 4; r++) {
                int m = m0 + wm + i*16 + quad*4 + r;
                float v = acc[i][j][r] + bv;
                if (mode == 3) {
                    outF[(size_t)m*DM + n] = v;
                } else {
                    int b = m >> 11, s = m & (SEQ-1);
                    int h = n >> 6,  d = n & (HD-1);
                    if (mode == 2)
                        outB[(((size_t)(b*NH + h))*HD + d)*SEQ + s] = f2b(v);
                    else
                        outB[(((size_t)(b*NH + h))*SEQ + s)*HD + d] = f2b(v);
                }
            }
        }
    }
}

__global__ __launch_bounds__(256) void gemm_qkv(
    const u16* __restrict__ x,
    const u16* __restrict__ WqT, const u16* __restrict__ WkT, const u16* __restrict__ WvT,
    const u16* __restrict__ bq, const u16* __restrict__ bk, const u16* __restrict__ bv,
    u16* __restrict__ qb, u16* __restrict__ kb, u16* __restrict__ vTb)
{
    int z = blockIdx.z;
    const u16* BT   = (z==0) ? WqT : (z==1) ? WkT : WvT;
    const u16* bias = (z==0) ? bq  : (z==1) ? bk  : bv;
    u16* outB       = (z==0) ? qb  : (z==1) ? kb  : vTb;
    gemm_body(x, BT, bias, outB, nullptr, (z==2) ? 2 : 0,
              blockIdx.x * 128, blockIdx.y * 128, threadIdx.x);
}

__global__ __launch_bounds__(256) void gemm_out(
    const u16* __restrict__ attn, const u16* __restrict__ WoT,
    const u16* __restrict__ bo, float* __restrict__ proj)
{
    gemm_body(attn, WoT, bo, nullptr, proj, 3,
              blockIdx.x * 128, blockIdx.y * 128, threadIdx.x);
}

// ---------------- retention: out = (QK^T * decay_mask) @ V ----------------
// q,k: [BH][SEQ][HD] ; vT: [BH][HD][SEQ] ; attn: [B][SEQ][DM]
// 128-row q-tiles; block handles paired tiles {x, 15-x} -> 34 j-iters always.
// LDS XOR swizzle: elem(row, col) at row*64 + ((col>>3 ^ (row&7))*8) + (col&7)
__global__ __launch_bounds__(256) void retention(
    const u16* __restrict__ q, const u16* __restrict__ k,
    const u16* __restrict__ vT, u16* __restrict__ attn)
{
    __shared__ u16 Ks[64*64];
    __shared__ u16 Vs[64*64];
    __shared__ u16 Ps[4][2*16*64];   // per-wave, 2 m-frags

    int x = blockIdx.x, bh = blockIdx.y;
    int t = threadIdx.x, w = t >> 6, l = t & 63;
    int c = l & 15, qd = l >> 4;

    const u16* qh = q  + (size_t)bh * SEQ * HD;
    const u16* kh = k  + (size_t)bh * SEQ * HD;
    const u16* vh = vT + (size_t)bh * HD * SEQ;

    // decay factor tables (fixed per block): wgt = base * D[m][r] * E[st]
    float D[2][4], E[4];
#pragma unroll
    for (int m = 0; m < 2; m++)
#pragma unroll
        for (int r = 0; r < 4; r++)
            D[m][r] = __expf((float)(m*16 + qd*4 + r) * LN_DECAY);
#pragma unroll
    for (int st = 0; st < 4; st++)
        E[st] = __expf(-(float)(st*16 + c) * LN_DECAY);

    int sr = t >> 3, sc8 = t & 7;
    int b = bh >> 4, h = bh & (NH-1);
    f32x4 zero = {0.f, 0.f, 0.f, 0.f};

#pragma unroll 1
    for (int phase = 0; phase < 2; phase++) {
        int tile = phase ? (15 - x) : x;
        int qbase = tile * 128;
        int iwave = qbase + w*32;

        short8 qf[2][2];
#pragma unroll
        for (int m = 0; m < 2; m++)
#pragma unroll
            for (int kk = 0; kk < 2; kk++)
                qf[m][kk] = *(const short8*)(qh + (size_t)(iwave + m*16 + c)*HD + kk*32 + qd*8);

        f32x4 oacc[2][4];
#pragma unroll
        for (int m = 0; m < 2; m++)
#pragma unroll
            for (int nt = 0; nt < 4; nt++)
                oacc[m][nt] = zero;

        int njt = 2*tile + 2;
#pragma unroll 1
        for (int jt = 0; jt < njt; jt++) {
            int jbase = jt * 64;
            __syncthreads();
            {
                int r0 = sr, r1 = sr + 32;
                *(short8*)(&Ks[r0*64 + ((sc8 ^ (r0&7))*8)]) = *(const short8*)(kh + (size_t)(jbase+r0)*HD + sc8*8);
                *(short8*)(&Ks[r1*64 + ((sc8 ^ (r1&7))*8)]) = *(const short8*)(kh + (size_t)(jbase+r1)*HD + sc8*8);
                *(short8*)(&Vs[r0*64 + ((sc8 ^ (r0&7))*8)]) = *(const short8*)(vh + (size_t)r0*SEQ + jbase + sc8*8);
                *(short8*)(&Vs[r1*64 + ((sc8 ^ (r1&7))*8)]) = *(const short8*)(vh + (size_t)r1*SEQ + jbase + sc8*8);
            }
            __syncthreads();

            // S = q @ k^T
            f32x4 sacc[2][4];
#pragma unroll
            for (int m = 0; m < 2; m++)
#pragma unroll
                for (int st = 0; st < 4; st++)
                    sacc[m][st] = zero;
#pragma unroll
            for (int kk = 0; kk < 2; kk++) {
#pragma unroll
                for (int st = 0; st < 4; st++) {
                    int row = st*16 + c;
                    short8 bf = *(const short8*)(&Ks[row*64 + (((kk*4+qd) ^ (row&7))*8)]);
                    sacc[0][st] = mfma16(qf[0][kk], bf, sacc[0][st]);
                    sacc[1][st] = mfma16(qf[1][kk], bf, sacc[1][st]);
                }
            }

            float base = __expf((float)(iwave - jbase) * LN_DECAY);
            // decay mask -> P (bf16) in per-wave swizzled LDS
#pragma unroll
            for (int m = 0; m < 2; m++) {
#pragma unroll
                for (int st = 0; st < 4; st++) {
                    int j = jbase + st*16 + c;
                    float bE = base * E[st];
#pragma unroll
                    for (int r = 0; r < 4; r++) {
                        int i = iwave + m*16 + qd*4 + r;
                        float val = (i >= j) ? sacc[m][st][r] * (bE * D[m][r]) : 0.0f;
                        int row = qd*4 + r;
                        int col = st*16 + c;
                        Ps[w][m*1024 + row*64 + (((col>>3) ^ (row&7))*8) + (col&7)] = f2b(val);
                    }
                }
            }
            asm volatile("s_waitcnt lgkmcnt(0)" ::: "memory");
            short8 pf[2][2];
#pragma unroll
            for (int m = 0; m < 2; m++)
#pragma unroll
                for (int kk = 0; kk < 2; kk++)
                    pf[m][kk] = *(const short8*)(&Ps[w][m*1024 + c*64 + (((kk*4+qd) ^ (c&7))*8)]);

            // O += P @ V
#pragma unroll
            for (int kk = 0; kk < 2; kk++) {
#pragma unroll
                for (int nt = 0; nt < 4; nt++) {
                    int row = nt*16 + c;
                    short8 vf = *(const short8*)(&Vs[row*64 + (((kk*4+qd) ^ (row&7))*8)]);
                    oacc[0][nt] = mfma16(pf[0][kk], vf, oacc[0][nt]);
                    oacc[1][nt] = mfma16(pf[1][kk], vf, oacc[1][nt]);
                }
            }
        }

#pragma unroll
        for (int m = 0; m < 2; m++)
#pragma unroll
            for (int nt = 0; nt < 4; nt++) {
                int d = h*HD + nt*16 + c;
#pragma unroll
                for (int r = 0; r < 4; r++) {
                    int s = iwave + m*16 + qd*4 + r;
                    attn[((size_t)(b*SEQ + s))*DM + d] = f2b(oacc[m][nt][r]);
                }
            }
    }
}

// ---------------- GroupNorm stats: two-stage reduction ----------------
__global__ __launch_bounds__(256) void gn_partial(
    const float* __restrict__ proj, float* __restrict__ partials)
{
    int bg = blockIdx.x;              // 0..31 : (b,g)
    int chunk = blockIdx.y;           // 0..15 : seq chunk of 128 rows
    int b = bg >> 4, g = bg & (NH-1);
    const float* base = proj + (size_t)b*SEQ*DM + g*HD;
    int tid = threadIdx.x;
    int rlane = tid & 15;
    int rrow  = tid >> 4;
    float s = 0.f, ss = 0.f;
#pragma unroll
    for (int it = 0; it < 8; it++) {
        int srow = chunk*128 + it*16 + rrow;
        f32x4 v = *(const f32x4*)(base + (size_t)srow*DM + rlane*4);
        s  += v[0] + v[1] + v[2] + v[3];
        ss += v[0]*v[0] + v[1]*v[1] + v[2]*v[2] + v[3]*v[3];
    }
#pragma unroll
    for (int off = 32; off > 0; off >>= 1) {
        s  += __shfl_down(s, off);
        ss += __shfl_down(ss, off);
    }
    __shared__ float red[8];
    int w = tid >> 6, l = tid & 63;
    if (l == 0) { red[w*2] = s; red[w*2+1] = ss; }
    __syncthreads();
    if (tid == 0) {
        float S  = red[0]+red[2]+red[4]+red[6];
        float SS = red[1]+red[3]+red[5]+red[7];
        partials[(bg*16 + chunk)*2]     = S;
        partials[(bg*16 + chunk)*2 + 1] = SS;
    }
}

__global__ __launch_bounds__(64) void gn_finalize(
    const float* __restrict__ partials, float* __restrict__ stats)
{
    int bg = blockIdx.x;
    int l = threadIdx.x;
    float s  = (l < 16) ? partials[(bg*16 + l)*2]     : 0.f;
    float ss = (l < 16) ? partials[(bg*16 + l)*2 + 1] : 0.f;
#pragma unroll
    for (int off = 8; off > 0; off >>= 1) {
        s  += __shfl_down(s, off);
        ss += __shfl_down(ss, off);
    }
    if (l == 0) {
        const float inv = 1.0f / (float)(SEQ*HD);
        float mu = s * inv;
        float var = ss * inv - mu*mu;
        stats[bg*2]   = mu;
        stats[bg*2+1] = rsqrtf(var + 1e-5f);
    }
}

__global__ __launch_bounds__(256) void gn_apply(
    const float* __restrict__ proj, const float* __restrict__ stats,
    const u16* __restrict__ gamma, const u16* __restrict__ beta,
    const int* __restrict__ flag, void* __restrict__ outv)
{
    int idx = blockIdx.x * 256 + threadIdx.x;
    int d = idx & (DM-1);
    int bs = idx >> 10;
    int b = bs >> 11;
    int g = d >> 6;
    float mu   = stats[(b*NH + g)*2];
    float rstd = stats[(b*NH + g)*2 + 1];
    float v = (proj[idx] - mu) * rstd * b2f(gamma[d]) + b2f(beta[d]);
    if (*flag) ((float*)outv)[idx] = v;
    else       ((u16*)outv)[idx]   = f2b(v);
}

// ---------------- launch ----------------
extern "C" void kernel_launch(void* const* d_in, const int* in_sizes, int n_in,
                              void* d_out, int out_size, void* d_ws, size_t ws_size,
                              hipStream_t stream) {
    const void* x     = d_in[0];
    const void* Wq    = d_in[1];
    const void* bq    = d_in[2];
    const void* Wk    = d_in[3];
    const void* bk    = d_in[4];
    const void* Wv    = d_in[5];
    const void* bv    = d_in[6];
    const void* Wo    = d_in[7];
    const void* bo    = d_in[8];
    const void* gamma = d_in[9];
    const void* beta  = d_in[10];

    const size_t MB = 1024*1024;
    char* ws = (char*)d_ws;
    int*   flag     = (int*)ws;
    u16*   bqc      = (u16*)(ws + 4096);
    u16*   bkc      = (u16*)(ws + 8192);
    u16*   bvc      = (u16*)(ws + 12288);
    u16*   boc      = (u16*)(ws + 16384);
    u16*   gammac   = (u16*)(ws + 20480);
    u16*   betac    = (u16*)(ws + 24576);
    float* stats    = (float*)(ws + 28672);
    float* partials = (float*)(ws + 32768);
    u16*   xc     = (u16*)(ws + 1*MB);
    u16*   WqT    = (u16*)(ws + 9*MB);
    u16*   WkT    = (u16*)(ws + 11*MB);
    u16*   WvT    = (u16*)(ws + 13*MB);
    u16*   WoT    = (u16*)(ws + 15*MB);
    u16*   qb     = (u16*)(ws + 17*MB);
    u16*   kb     = (u16*)(ws + 25*MB);
    u16*   vTb    = (u16*)(ws + 33*MB);
    u16*   attn   = (u16*)(ws + 41*MB);
    float* proj   = (float*)(ws + 17*MB); // overlays qb/kb (free after retention)

    detect_dtype<<<1, 64, 0, stream>>>((const u16*)Wq, flag);
    convert_x<<<4096, 256, 0, stream>>>(x, flag, xc);
    convert_small<<<6, 256, 0, stream>>>(bq, bk, bv, bo, gamma, beta, flag,
                                         bqc, bkc, bvc, boc, gammac, betac);
    transpose4<<<dim3(32, 32, 4), 256, 0, stream>>>(Wq, Wk, Wv, Wo, flag, WqT, WkT, WvT, WoT);
    gemm_qkv<<<dim3(32, 8, 3), 256, 0, stream>>>(xc, WqT, WkT, WvT, bqc, bkc, bvc, qb, kb, vTb);
    retention<<<dim3(8, 32), 256, 0, stream>>>(qb, kb, vTb, attn);
    gemm_out<<<dim3(32, 8), 256, 0, stream>>>(attn, WoT, boc, proj);
    gn_partial<<<dim3(32, 16), 256, 0, stream>>>(proj, partials);
    gn_finalize<<<32, 64, 0, stream>>>(partials, stats);
    gn_apply<<<(SEQ*DM*2)/256, 256, 0, stream>>>(proj, stats, gammac, betac, flag, d_out);
}

// Round 6
// 202.311 us; speedup vs baseline: 1.3686x; 1.3686x over previous
//
#include <hip/hip_runtime.h>
#include <hip/hip_bf16.h>

typedef unsigned short u16;
typedef __attribute__((ext_vector_type(8))) short short8;
typedef __attribute__((ext_vector_type(4))) float f32x4;
typedef __attribute__((ext_vector_type(4))) unsigned short u16x4;

#define SEQ 2048
#define NH 16
#define HD 64
#define DM 1024
#define LN_DECAY (-0.051293294387550536f)
// decay window: contributions beyond distance ~256 are < 1e-5 of output std
#define WIN_TILES 4

__device__ __forceinline__ float b2f(u16 u) {
    return __uint_as_float(((unsigned int)u) << 16);
}
__device__ __forceinline__ u16 f2b(float f) {
    unsigned int u = __float_as_uint(f);
    u += 0x7fffu + ((u >> 16) & 1u);   // round-to-nearest-even
    return (u16)(u >> 16);
}
__device__ __forceinline__ f32x4 mfma16(short8 a, short8 b, f32x4 c) {
    return __builtin_amdgcn_mfma_f32_16x16x32_bf16(a, b, c, 0, 0, 0);
}

// ---------------- dtype detection ----------------
__global__ __launch_bounds__(64) void detect_dtype(const u16* __restrict__ W,
                                                   int* __restrict__ flag) {
    int t = threadIdx.x;
    int hit = 0;
    for (int i = t; i < 512; i += 64) {
        u16 u = W[2 * i];
        int e = (u >> 7) & 0xFF;
        if (e >= 0xC0) hit = 1;
    }
    unsigned long long m = __ballot(hit);
    if (t == 0) *flag = (m != 0ULL) ? 1 : 0;
}

// ---------------- input canonicalization to bf16 ----------------
__global__ __launch_bounds__(256) void convert_x(const void* __restrict__ x,
                                                 const int* __restrict__ flag,
                                                 u16* __restrict__ xc) {
    int i = (blockIdx.x * 256 + threadIdx.x) * 4;
    if (*flag) {
        f32x4 v = *(const f32x4*)((const float*)x + i);
        u16x4 o = { f2b(v[0]), f2b(v[1]), f2b(v[2]), f2b(v[3]) };
        *(u16x4*)(xc + i) = o;
    } else {
        *(u16x4*)(xc + i) = *(const u16x4*)((const u16*)x + i);
    }
}

__global__ __launch_bounds__(256) void convert_small(
    const void* __restrict__ p0, const void* __restrict__ p1,
    const void* __restrict__ p2, const void* __restrict__ p3,
    const void* __restrict__ p4, const void* __restrict__ p5,
    const int* __restrict__ flag,
    u16* __restrict__ o0, u16* __restrict__ o1, u16* __restrict__ o2,
    u16* __restrict__ o3, u16* __restrict__ o4, u16* __restrict__ o5) {
    const void* in; u16* out;
    switch (blockIdx.x) {
        case 0: in = p0; out = o0; break;
        case 1: in = p1; out = o1; break;
        case 2: in = p2; out = o2; break;
        case 3: in = p3; out = o3; break;
        case 4: in = p4; out = o4; break;
        default: in = p5; out = o5; break;
    }
    int i = threadIdx.x * 4;
    if (*flag) {
        f32x4 v = *(const f32x4*)((const float*)in + i);
        u16x4 o = { f2b(v[0]), f2b(v[1]), f2b(v[2]), f2b(v[3]) };
        *(u16x4*)(out + i) = o;
    } else {
        *(u16x4*)(out + i) = *(const u16x4*)((const u16*)in + i);
    }
}

// ---------------- weight transpose+convert: W[k][n] -> WT[n][k] bf16 -------
__global__ __launch_bounds__(256) void transpose4(
    const void* __restrict__ W0, const void* __restrict__ W1,
    const void* __restrict__ W2, const void* __restrict__ W3,
    const int* __restrict__ flag,
    u16* __restrict__ T0, u16* __restrict__ T1,
    u16* __restrict__ T2, u16* __restrict__ T3)
{
    __shared__ u16 tile[32][33];
    const void* W; u16* T;
    int z = blockIdx.z;
    if (z == 0)      { W = W0; T = T0; }
    else if (z == 1) { W = W1; T = T1; }
    else if (z == 2) { W = W2; T = T2; }
    else             { W = W3; T = T3; }
    int fl = *flag;
    int t = threadIdx.x;
    int r = t >> 5, c = t & 31;
    int bn = blockIdx.x * 32, bk = blockIdx.y * 32;
#pragma unroll
    for (int i = 0; i < 4; i++) {
        size_t idx = (size_t)(bk + r + i*8) * DM + bn + c;
        tile[r + i*8][c] = fl ? f2b(((const float*)W)[idx]) : ((const u16*)W)[idx];
    }
    __syncthreads();
#pragma unroll
    for (int i = 0; i < 4; i++)
        T[(size_t)(bn + r + i*8) * DM + bk + c] = tile[c][r + i*8];
}

// ---------------- 128x128 MFMA GEMM body ----------------
__device__ __forceinline__ void gemm_body(
    const u16* __restrict__ A, const u16* __restrict__ BT,
    const u16* __restrict__ bias, u16* __restrict__ outB,
    float* __restrict__ outF, int mode,
    int m0, int n0, int t)
{
    __shared__ u16 As[128][40];
    __shared__ u16 Bs[128][40];
    int w = t >> 6, l = t & 63;
    int lane16 = l & 15, quad = l >> 4;
    int wm = (w >> 1) * 64, wn = (w & 1) * 64;
    int lr = t >> 2, lu = t & 3;

    f32x4 zero = {0.f, 0.f, 0.f, 0.f};
    f32x4 acc[4][4];
#pragma unroll
    for (int i = 0; i < 4; i++)
#pragma unroll
        for (int j = 0; j < 4; j++)
            acc[i][j] = zero;

    for (int k0 = 0; k0 < DM; k0 += 32) {
        __syncthreads();
        *(short8*)(&As[lr][lu*8])      = *(const short8*)(A  + (size_t)(m0+lr)   *DM + k0 + lu*8);
        *(short8*)(&As[lr+64][lu*8])   = *(const short8*)(A  + (size_t)(m0+lr+64)*DM + k0 + lu*8);
        *(short8*)(&Bs[lr][lu*8])      = *(const short8*)(BT + (size_t)(n0+lr)   *DM + k0 + lu*8);
        *(short8*)(&Bs[lr+64][lu*8])   = *(const short8*)(BT + (size_t)(n0+lr+64)*DM + k0 + lu*8);
        __syncthreads();
        short8 af[4], bf[4];
#pragma unroll
        for (int i = 0; i < 4; i++) {
            af[i] = *(const short8*)(&As[wm + i*16 + lane16][quad*8]);
            bf[i] = *(const short8*)(&Bs[wn + i*16 + lane16][quad*8]);
        }
#pragma unroll
        for (int i = 0; i < 4; i++)
#pragma unroll
            for (int j = 0; j < 4; j++)
                acc[i][j] = mfma16(af[i], bf[j], acc[i][j]);
    }

#pragma unroll
    for (int i = 0; i < 4; i++) {
#pragma unroll
        for (int j = 0; j < 4; j++) {
            int n = n0 + wn + j*16 + lane16;
            float bv = b2f(bias[n]);
#pragma unroll
            for (int r = 0; r < 4; r++) {
                int m = m0 + wm + i*16 + quad*4 + r;
                float v = acc[i][j][r] + bv;
                if (mode == 3) {
                    outF[(size_t)m*DM + n] = v;
                } else {
                    int b = m >> 11, s = m & (SEQ-1);
                    int h = n >> 6,  d = n & (HD-1);
                    if (mode == 2)
                        outB[(((size_t)(b*NH + h))*HD + d)*SEQ + s] = f2b(v);
                    else
                        outB[(((size_t)(b*NH + h))*SEQ + s)*HD + d] = f2b(v);
                }
            }
        }
    }
}

__global__ __launch_bounds__(256) void gemm_qkv(
    const u16* __restrict__ x,
    const u16* __restrict__ WqT, const u16* __restrict__ WkT, const u16* __restrict__ WvT,
    const u16* __restrict__ bq, const u16* __restrict__ bk, const u16* __restrict__ bv,
    u16* __restrict__ qb, u16* __restrict__ kb, u16* __restrict__ vTb)
{
    int z = blockIdx.z;
    const u16* BT   = (z==0) ? WqT : (z==1) ? WkT : WvT;
    const u16* bias = (z==0) ? bq  : (z==1) ? bk  : bv;
    u16* outB       = (z==0) ? qb  : (z==1) ? kb  : vTb;
    gemm_body(x, BT, bias, outB, nullptr, (z==2) ? 2 : 0,
              blockIdx.x * 128, blockIdx.y * 128, threadIdx.x);
}

__global__ __launch_bounds__(256) void gemm_out(
    const u16* __restrict__ attn, const u16* __restrict__ WoT,
    const u16* __restrict__ bo, float* __restrict__ proj)
{
    gemm_body(attn, WoT, bo, nullptr, proj, 3,
              blockIdx.x * 128, blockIdx.y * 128, threadIdx.x);
}

// ---------------- retention: out = (QK^T * decay_mask) @ V ----------------
// Sliding-window: decay^d < 2e-6 for d > 256, so each 64-row q-tile only
// processes j-tiles [qt-WIN_TILES, qt]. Grid 32x32 = 1024 blocks (4/CU).
// LDS XOR swizzle: elem(row,col) at row*64 + ((col>>3 ^ (row&7))*8) + (col&7)
__global__ __launch_bounds__(256) void retention(
    const u16* __restrict__ q, const u16* __restrict__ k,
    const u16* __restrict__ vT, u16* __restrict__ attn)
{
    __shared__ u16 Ks[64*64];
    __shared__ u16 Vs[64*64];
    __shared__ u16 Ps[4][16*64];   // per-wave P tile

    int qt = blockIdx.x, bh = blockIdx.y;
    int t = threadIdx.x, w = t >> 6, l = t & 63;
    int c = l & 15, qd = l >> 4;
    int qbase = qt * 64;
    int iwave = qbase + w*16;

    const u16* qh = q  + (size_t)bh * SEQ * HD;
    const u16* kh = k  + (size_t)bh * SEQ * HD;
    const u16* vh = vT + (size_t)bh * HD * SEQ;

    // decay tables: wgt(i,j) = base(iter) * D[r] * E[st]
    float D[4], E[4];
#pragma unroll
    for (int r = 0; r < 4; r++)
        D[r] = __expf((float)(qd*4 + r) * LN_DECAY);
#pragma unroll
    for (int st = 0; st < 4; st++)
        E[st] = __expf(-(float)(st*16 + c) * LN_DECAY);

    int sr = t >> 3, sc8 = t & 7;

    short8 qf[2];
#pragma unroll
    for (int kk = 0; kk < 2; kk++)
        qf[kk] = *(const short8*)(qh + (size_t)(iwave + c)*HD + kk*32 + qd*8);

    f32x4 zero = {0.f, 0.f, 0.f, 0.f};
    f32x4 oacc[4] = {zero, zero, zero, zero};

    int jt0 = (qt > WIN_TILES) ? (qt - WIN_TILES) : 0;
#pragma unroll 1
    for (int jt = jt0; jt <= qt; jt++) {
        int jbase = jt * 64;
        __syncthreads();
        {
            int r0 = sr, r1 = sr + 32;
            *(short8*)(&Ks[r0*64 + ((sc8 ^ (r0&7))*8)]) = *(const short8*)(kh + (size_t)(jbase+r0)*HD + sc8*8);
            *(short8*)(&Ks[r1*64 + ((sc8 ^ (r1&7))*8)]) = *(const short8*)(kh + (size_t)(jbase+r1)*HD + sc8*8);
            *(short8*)(&Vs[r0*64 + ((sc8 ^ (r0&7))*8)]) = *(const short8*)(vh + (size_t)r0*SEQ + jbase + sc8*8);
            *(short8*)(&Vs[r1*64 + ((sc8 ^ (r1&7))*8)]) = *(const short8*)(vh + (size_t)r1*SEQ + jbase + sc8*8);
        }
        __syncthreads();

        // S = q @ k^T   (C layout: row=i=qd*4+r, col=j=c)
        f32x4 sacc[4] = {zero, zero, zero, zero};
#pragma unroll
        for (int kk = 0; kk < 2; kk++) {
#pragma unroll
            for (int st = 0; st < 4; st++) {
                int row = st*16 + c;
                short8 bf = *(const short8*)(&Ks[row*64 + (((kk*4+qd) ^ (row&7))*8)]);
                sacc[st] = mfma16(qf[kk], bf, sacc[st]);
            }
        }

        float base = __expf((float)(iwave - jbase) * LN_DECAY);
#pragma unroll
        for (int st = 0; st < 4; st++) {
            int j = jbase + st*16 + c;
            float bE = base * E[st];
#pragma unroll
            for (int r = 0; r < 4; r++) {
                int i = iwave + qd*4 + r;
                float val = (i >= j) ? sacc[st][r] * (bE * D[r]) : 0.0f;
                int row = qd*4 + r;
                int col = st*16 + c;
                Ps[w][row*64 + (((col>>3) ^ (row&7))*8) + (col&7)] = f2b(val);
            }
        }
        asm volatile("s_waitcnt lgkmcnt(0)" ::: "memory");
        short8 pf[2];
#pragma unroll
        for (int kk = 0; kk < 2; kk++)
            pf[kk] = *(const short8*)(&Ps[w][c*64 + (((kk*4+qd) ^ (c&7))*8)]);

        // O += P @ V
#pragma unroll
        for (int kk = 0; kk < 2; kk++) {
#pragma unroll
            for (int nt = 0; nt < 4; nt++) {
                int row = nt*16 + c;
                short8 vf = *(const short8*)(&Vs[row*64 + (((kk*4+qd) ^ (row&7))*8)]);
                oacc[nt] = mfma16(pf[kk], vf, oacc[nt]);
            }
        }
    }

    int b = bh >> 4, h = bh & (NH-1);
#pragma unroll
    for (int nt = 0; nt < 4; nt++) {
        int d = h*HD + nt*16 + c;
#pragma unroll
        for (int r = 0; r < 4; r++) {
            int s = iwave + qd*4 + r;
            attn[((size_t)(b*SEQ + s))*DM + d] = f2b(oacc[nt][r]);
        }
    }
}

// ---------------- GroupNorm stats: two-stage reduction ----------------
__global__ __launch_bounds__(256) void gn_partial(
    const float* __restrict__ proj, float* __restrict__ partials)
{
    int bg = blockIdx.x;              // 0..31 : (b,g)
    int chunk = blockIdx.y;           // 0..15 : seq chunk of 128 rows
    int b = bg >> 4, g = bg & (NH-1);
    const float* base = proj + (size_t)b*SEQ*DM + g*HD;
    int tid = threadIdx.x;
    int rlane = tid & 15;
    int rrow  = tid >> 4;
    float s = 0.f, ss = 0.f;
#pragma unroll
    for (int it = 0; it < 8; it++) {
        int srow = chunk*128 + it*16 + rrow;
        f32x4 v = *(const f32x4*)(base + (size_t)srow*DM + rlane*4);
        s  += v[0] + v[1] + v[2] + v[3];
        ss += v[0]*v[0] + v[1]*v[1] + v[2]*v[2] + v[3]*v[3];
    }
#pragma unroll
    for (int off = 32; off > 0; off >>= 1) {
        s  += __shfl_down(s, off);
        ss += __shfl_down(ss, off);
    }
    __shared__ float red[8];
    int w = tid >> 6, l = tid & 63;
    if (l == 0) { red[w*2] = s; red[w*2+1] = ss; }
    __syncthreads();
    if (tid == 0) {
        float S  = red[0]+red[2]+red[4]+red[6];
        float SS = red[1]+red[3]+red[5]+red[7];
        partials[(bg*16 + chunk)*2]     = S;
        partials[(bg*16 + chunk)*2 + 1] = SS;
    }
}

__global__ __launch_bounds__(64) void gn_finalize(
    const float* __restrict__ partials, float* __restrict__ stats)
{
    int bg = blockIdx.x;
    int l = threadIdx.x;
    float s  = (l < 16) ? partials[(bg*16 + l)*2]     : 0.f;
    float ss = (l < 16) ? partials[(bg*16 + l)*2 + 1] : 0.f;
#pragma unroll
    for (int off = 8; off > 0; off >>= 1) {
        s  += __shfl_down(s, off);
        ss += __shfl_down(ss, off);
    }
    if (l == 0) {
        const float inv = 1.0f / (float)(SEQ*HD);
        float mu = s * inv;
        float var = ss * inv - mu*mu;
        stats[bg*2]   = mu;
        stats[bg*2+1] = rsqrtf(var + 1e-5f);
    }
}

__global__ __launch_bounds__(256) void gn_apply(
    const float* __restrict__ proj, const float* __restrict__ stats,
    const u16* __restrict__ gamma, const u16* __restrict__ beta,
    const int* __restrict__ flag, void* __restrict__ outv)
{
    int idx = blockIdx.x * 256 + threadIdx.x;
    int d = idx & (DM-1);
    int bs = idx >> 10;
    int b = bs >> 11;
    int g = d >> 6;
    float mu   = stats[(b*NH + g)*2];
    float rstd = stats[(b*NH + g)*2 + 1];
    float v = (proj[idx] - mu) * rstd * b2f(gamma[d]) + b2f(beta[d]);
    if (*flag) ((float*)outv)[idx] = v;
    else       ((u16*)outv)[idx]   = f2b(v);
}

// ---------------- launch ----------------
extern "C" void kernel_launch(void* const* d_in, const int* in_sizes, int n_in,
                              void* d_out, int out_size, void* d_ws, size_t ws_size,
                              hipStream_t stream) {
    const void* x     = d_in[0];
    const void* Wq    = d_in[1];
    const void* bq    = d_in[2];
    const void* Wk    = d_in[3];
    const void* bk    = d_in[4];
    const void* Wv    = d_in[5];
    const void* bv    = d_in[6];
    const void* Wo    = d_in[7];
    const void* bo    = d_in[8];
    const void* gamma = d_in[9];
    const void* beta  = d_in[10];

    const size_t MB = 1024*1024;
    char* ws = (char*)d_ws;
    int*   flag     = (int*)ws;
    u16*   bqc      = (u16*)(ws + 4096);
    u16*   bkc      = (u16*)(ws + 8192);
    u16*   bvc      = (u16*)(ws + 12288);
    u16*   boc      = (u16*)(ws + 16384);
    u16*   gammac   = (u16*)(ws + 20480);
    u16*   betac    = (u16*)(ws + 24576);
    float* stats    = (float*)(ws + 28672);
    float* partials = (float*)(ws + 32768);
    u16*   xc     = (u16*)(ws + 1*MB);
    u16*   WqT    = (u16*)(ws + 9*MB);
    u16*   WkT    = (u16*)(ws + 11*MB);
    u16*   WvT    = (u16*)(ws + 13*MB);
    u16*   WoT    = (u16*)(ws + 15*MB);
    u16*   qb     = (u16*)(ws + 17*MB);
    u16*   kb     = (u16*)(ws + 25*MB);
    u16*   vTb    = (u16*)(ws + 33*MB);
    u16*   attn   = (u16*)(ws + 41*MB);
    float* proj   = (float*)(ws + 17*MB); // overlays qb/kb (free after retention)

    detect_dtype<<<1, 64, 0, stream>>>((const u16*)Wq, flag);
    convert_x<<<4096, 256, 0, stream>>>(x, flag, xc);
    convert_small<<<6, 256, 0, stream>>>(bq, bk, bv, bo, gamma, beta, flag,
                                         bqc, bkc, bvc, boc, gammac, betac);
    transpose4<<<dim3(32, 32, 4), 256, 0, stream>>>(Wq, Wk, Wv, Wo, flag, WqT, WkT, WvT, WoT);
    gemm_qkv<<<dim3(32, 8, 3), 256, 0, stream>>>(xc, WqT, WkT, WvT, bqc, bkc, bvc, qb, kb, vTb);
    retention<<<dim3(32, 32), 256, 0, stream>>>(qb, kb, vTb, attn);
    gemm_out<<<dim3(32, 8), 256, 0, stream>>>(attn, WoT, boc, proj);
    gn_partial<<<dim3(32, 16), 256, 0, stream>>>(proj, partials);
    gn_finalize<<<32, 64, 0, stream>>>(partials, stats);
    gn_apply<<<(SEQ*DM*2)/256, 256, 0, stream>>>(proj, stats, gammac, betac, flag, d_out);
}

// Round 8
// 193.869 us; speedup vs baseline: 1.4281x; 1.0435x over previous
//
#include <hip/hip_runtime.h>
#include <hip/hip_bf16.h>

typedef unsigned short u16;
typedef __attribute__((ext_vector_type(8))) short short8;
typedef __attribute__((ext_vector_type(4))) float f32x4;
typedef __attribute__((ext_vector_type(4))) unsigned short u16x4;

#define SEQ 2048
#define NH 16
#define HD 64
#define DM 1024
#define LN_DECAY (-0.051293294387550536f)
// decay window: contributions beyond distance ~256 are < 1e-5 of output std
#define WIN_TILES 4

__device__ __forceinline__ float b2f(u16 u) {
    return __uint_as_float(((unsigned int)u) << 16);
}
__device__ __forceinline__ u16 f2b(float f) {
    unsigned int u = __float_as_uint(f);
    u += 0x7fffu + ((u >> 16) & 1u);   // round-to-nearest-even
    return (u16)(u >> 16);
}
__device__ __forceinline__ f32x4 mfma16(short8 a, short8 b, f32x4 c) {
    return __builtin_amdgcn_mfma_f32_16x16x32_bf16(a, b, c, 0, 0, 0);
}
// async global->LDS, 16B per lane; dest = wave-uniform base + lane*16
__device__ __forceinline__ void gld_lds16(const u16* g, u16* l) {
    __builtin_amdgcn_global_load_lds(
        (const __attribute__((address_space(1))) void*)g,
        (__attribute__((address_space(3))) void*)l, 16, 0, 0);
}

// ---------------- dtype detection ----------------
__global__ __launch_bounds__(64) void detect_dtype(const u16* __restrict__ W,
                                                   int* __restrict__ flag) {
    int t = threadIdx.x;
    int hit = 0;
    for (int i = t; i < 512; i += 64) {
        u16 u = W[2 * i];
        int e = (u >> 7) & 0xFF;
        if (e >= 0xC0) hit = 1;
    }
    unsigned long long m = __ballot(hit);
    if (t == 0) *flag = (m != 0ULL) ? 1 : 0;
}

// ---------------- input canonicalization to bf16 ----------------
__global__ __launch_bounds__(256) void convert_x(const void* __restrict__ x,
                                                 const int* __restrict__ flag,
                                                 u16* __restrict__ xc) {
    int i = (blockIdx.x * 256 + threadIdx.x) * 4;
    if (*flag) {
        f32x4 v = *(const f32x4*)((const float*)x + i);
        u16x4 o = { f2b(v[0]), f2b(v[1]), f2b(v[2]), f2b(v[3]) };
        *(u16x4*)(xc + i) = o;
    } else {
        *(u16x4*)(xc + i) = *(const u16x4*)((const u16*)x + i);
    }
}

__global__ __launch_bounds__(256) void convert_small(
    const void* __restrict__ p0, const void* __restrict__ p1,
    const void* __restrict__ p2, const void* __restrict__ p3,
    const void* __restrict__ p4, const void* __restrict__ p5,
    const int* __restrict__ flag,
    u16* __restrict__ o0, u16* __restrict__ o1, u16* __restrict__ o2,
    u16* __restrict__ o3, u16* __restrict__ o4, u16* __restrict__ o5) {
    const void* in; u16* out;
    switch (blockIdx.x) {
        case 0: in = p0; out = o0; break;
        case 1: in = p1; out = o1; break;
        case 2: in = p2; out = o2; break;
        case 3: in = p3; out = o3; break;
        case 4: in = p4; out = o4; break;
        default: in = p5; out = o5; break;
    }
    int i = threadIdx.x * 4;
    if (*flag) {
        f32x4 v = *(const f32x4*)((const float*)in + i);
        u16x4 o = { f2b(v[0]), f2b(v[1]), f2b(v[2]), f2b(v[3]) };
        *(u16x4*)(out + i) = o;
    } else {
        *(u16x4*)(out + i) = *(const u16x4*)((const u16*)in + i);
    }
}

// ---------------- weight transpose+convert: W[k][n] -> WT[n][k] bf16 -------
__global__ __launch_bounds__(256) void transpose4(
    const void* __restrict__ W0, const void* __restrict__ W1,
    const void* __restrict__ W2, const void* __restrict__ W3,
    const int* __restrict__ flag,
    u16* __restrict__ T0, u16* __restrict__ T1,
    u16* __restrict__ T2, u16* __restrict__ T3)
{
    __shared__ u16 tile[32][33];
    const void* W; u16* T;
    int z = blockIdx.z;
    if (z == 0)      { W = W0; T = T0; }
    else if (z == 1) { W = W1; T = T1; }
    else if (z == 2) { W = W2; T = T2; }
    else             { W = W3; T = T3; }
    int fl = *flag;
    int t = threadIdx.x;
    int r = t >> 5, c = t & 31;
    int bn = blockIdx.x * 32, bk = blockIdx.y * 32;
#pragma unroll
    for (int i = 0; i < 4; i++) {
        size_t idx = (size_t)(bk + r + i*8) * DM + bn + c;
        tile[r + i*8][c] = fl ? f2b(((const float*)W)[idx]) : ((const u16*)W)[idx];
    }
    __syncthreads();
#pragma unroll
    for (int i = 0; i < 4; i++)
        T[(size_t)(bn + r + i*8) * DM + bk + c] = tile[c][r + i*8];
}

// ---------------- 128x128 MFMA GEMM body ----------------
// Packed LDS [128][32] (global_load_lds forbids padding). Source-side XOR
// swizzle: elem A[row][k0+c*8+e] lives at LDS[row*32 + (c ^ ((row>>1)&3))*8 + e]
// -> b128 frag reads alias only 2-way (free).
// Row halves: rows 0-63 at LDS[0..2048), rows 64-127 at LDS[2048..4096) (u16 idx).
__device__ __forceinline__ void gemm_body(
    const u16* __restrict__ A, const u16* __restrict__ BT,
    const u16* __restrict__ bias, u16* __restrict__ outB,
    float* __restrict__ outF, int mode,
    int m0, int n0, int t)
{
    __shared__ u16 As[128*32];
    __shared__ u16 Bs[128*32];
    int w = t >> 6, l = t & 63;
    int lane16 = l & 15, quad = l >> 4;
    int wm = (w >> 1) * 64, wn = (w & 1) * 64;

    int srow   = t >> 2;                      // 0..63 staging row
    int schunk = (t & 3) ^ ((t >> 3) & 3);    // swizzled source chunk

    f32x4 zero = {0.f, 0.f, 0.f, 0.f};
    f32x4 acc[4][4];
#pragma unroll
    for (int i = 0; i < 4; i++)
#pragma unroll
        for (int j = 0; j < 4; j++)
            acc[i][j] = zero;

    const u16* a0 = A  + (size_t)(m0 + srow)      * DM + schunk*8;
    const u16* a1 = A  + (size_t)(m0 + srow + 64) * DM + schunk*8;
    const u16* b0 = BT + (size_t)(n0 + srow)      * DM + schunk*8;
    const u16* b1 = BT + (size_t)(n0 + srow + 64) * DM + schunk*8;

    for (int k0 = 0; k0 < DM; k0 += 32) {
        __syncthreads();
        gld_lds16(a0 + k0, &As[t*8]);
        gld_lds16(a1 + k0, &As[2048 + t*8]);
        gld_lds16(b0 + k0, &Bs[t*8]);
        gld_lds16(b1 + k0, &Bs[2048 + t*8]);
        __syncthreads();
        short8 af[4], bf[4];
#pragma unroll
        for (int i = 0; i < 4; i++) {
            int ra = wm + i*16 + lane16;
            int rb = wn + i*16 + lane16;
            af[i] = *(const short8*)(&As[ra*32 + ((quad ^ ((ra>>1)&3))*8)]);
            bf[i] = *(const short8*)(&Bs[rb*32 + ((quad ^ ((rb>>1)&3))*8)]);
        }
#pragma unroll
        for (int i = 0; i < 4; i++)
#pragma unroll
            for (int j = 0; j < 4; j++)
                acc[i][j] = mfma16(af[i], bf[j], acc[i][j]);
    }

#pragma unroll
    for (int i = 0; i < 4; i++) {
#pragma unroll
        for (int j = 0; j < 4; j++) {
            int n = n0 + wn + j*16 + lane16;
            float bv = b2f(bias[n]);
#pragma unroll
            for (int r = 0; r < 4; r++) {
                int m = m0 + wm + i*16 + quad*4 + r;
                float v = acc[i][j][r] + bv;
                if (mode == 3) {
                    outF[(size_t)m*DM + n] = v;
                } else {
                    int b = m >> 11, s = m & (SEQ-1);
                    int h = n >> 6,  d = n & (HD-1);
                    if (mode == 2)
                        outB[(((size_t)(b*NH + h))*HD + d)*SEQ + s] = f2b(v);
                    else
                        outB[(((size_t)(b*NH + h))*SEQ + s)*HD + d] = f2b(v);
                }
            }
        }
    }
}

__global__ __launch_bounds__(256) void gemm_qkv(
    const u16* __restrict__ x,
    const u16* __restrict__ WqT, const u16* __restrict__ WkT, const u16* __restrict__ WvT,
    const u16* __restrict__ bq, const u16* __restrict__ bk, const u16* __restrict__ bv,
    u16* __restrict__ qb, u16* __restrict__ kb, u16* __restrict__ vTb)
{
    int z = blockIdx.z;
    const u16* BT   = (z==0) ? WqT : (z==1) ? WkT : WvT;
    const u16* bias = (z==0) ? bq  : (z==1) ? bk  : bv;
    u16* outB       = (z==0) ? qb  : (z==1) ? kb  : vTb;
    gemm_body(x, BT, bias, outB, nullptr, (z==2) ? 2 : 0,
              blockIdx.x * 128, blockIdx.y * 128, threadIdx.x);
}

__global__ __launch_bounds__(256) void gemm_out(
    const u16* __restrict__ attn, const u16* __restrict__ WoT,
    const u16* __restrict__ bo, float* __restrict__ proj)
{
    gemm_body(attn, WoT, bo, nullptr, proj, 3,
              blockIdx.x * 128, blockIdx.y * 128, threadIdx.x);
}

// ---------------- retention: out = (QK^T * decay_mask) @ V ----------------
// Sliding-window: decay^d < 2e-6 for d > 256, so each 64-row q-tile only
// processes j-tiles [qt-WIN_TILES, qt]. Grid 32x32 = 1024 blocks (4/CU).
// LDS XOR swizzle: elem(row,col) at row*64 + ((col>>3 ^ (row&7))*8) + (col&7)
__global__ __launch_bounds__(256) void retention(
    const u16* __restrict__ q, const u16* __restrict__ k,
    const u16* __restrict__ vT, u16* __restrict__ attn)
{
    __shared__ u16 Ks[64*64];
    __shared__ u16 Vs[64*64];
    __shared__ u16 Ps[4][16*64];   // per-wave P tile

    int qt = blockIdx.x, bh = blockIdx.y;
    int t = threadIdx.x, w = t >> 6, l = t & 63;
    int c = l & 15, qd = l >> 4;
    int qbase = qt * 64;
    int iwave = qbase + w*16;

    const u16* qh = q  + (size_t)bh * SEQ * HD;
    const u16* kh = k  + (size_t)bh * SEQ * HD;
    const u16* vh = vT + (size_t)bh * HD * SEQ;

    // decay tables: wgt(i,j) = base(iter) * D[r] * E[st]
    float D[4], E[4];
#pragma unroll
    for (int r = 0; r < 4; r++)
        D[r] = __expf((float)(qd*4 + r) * LN_DECAY);
#pragma unroll
    for (int st = 0; st < 4; st++)
        E[st] = __expf(-(float)(st*16 + c) * LN_DECAY);

    int sr = t >> 3, sc8 = t & 7;

    short8 qf[2];
#pragma unroll
    for (int kk = 0; kk < 2; kk++)
        qf[kk] = *(const short8*)(qh + (size_t)(iwave + c)*HD + kk*32 + qd*8);

    f32x4 zero = {0.f, 0.f, 0.f, 0.f};
    f32x4 oacc[4] = {zero, zero, zero, zero};

    int jt0 = (qt > WIN_TILES) ? (qt - WIN_TILES) : 0;
#pragma unroll 1
    for (int jt = jt0; jt <= qt; jt++) {
        int jbase = jt * 64;
        __syncthreads();
        {
            int r0 = sr, r1 = sr + 32;
            *(short8*)(&Ks[r0*64 + ((sc8 ^ (r0&7))*8)]) = *(const short8*)(kh + (size_t)(jbase+r0)*HD + sc8*8);
            *(short8*)(&Ks[r1*64 + ((sc8 ^ (r1&7))*8)]) = *(const short8*)(kh + (size_t)(jbase+r1)*HD + sc8*8);
            *(short8*)(&Vs[r0*64 + ((sc8 ^ (r0&7))*8)]) = *(const short8*)(vh + (size_t)r0*SEQ + jbase + sc8*8);
            *(short8*)(&Vs[r1*64 + ((sc8 ^ (r1&7))*8)]) = *(const short8*)(vh + (size_t)(r1)*SEQ + jbase + sc8*8);
        }
        __syncthreads();

        // S = q @ k^T   (C layout: row=i=qd*4+r, col=j=c)
        f32x4 sacc[4] = {zero, zero, zero, zero};
#pragma unroll
        for (int kk = 0; kk < 2; kk++) {
#pragma unroll
            for (int st = 0; st < 4; st++) {
                int row = st*16 + c;
                short8 bf = *(const short8*)(&Ks[row*64 + (((kk*4+qd) ^ (row&7))*8)]);
                sacc[st] = mfma16(qf[kk], bf, sacc[st]);
            }
        }

        float base = __expf((float)(iwave - jbase) * LN_DECAY);
#pragma unroll
        for (int st = 0; st < 4; st++) {
            int j = jbase + st*16 + c;
            float bE = base * E[st];
#pragma unroll
            for (int r = 0; r < 4; r++) {
                int i = iwave + qd*4 + r;
                float val = (i >= j) ? sacc[st][r] * (bE * D[r]) : 0.0f;
                int row = qd*4 + r;
                int col = st*16 + c;
                Ps[w][row*64 + (((col>>3) ^ (row&7))*8) + (col&7)] = f2b(val);
            }
        }
        asm volatile("s_waitcnt lgkmcnt(0)" ::: "memory");
        short8 pf[2];
#pragma unroll
        for (int kk = 0; kk < 2; kk++)
            pf[kk] = *(const short8*)(&Ps[w][c*64 + (((kk*4+qd) ^ (c&7))*8)]);

        // O += P @ V
#pragma unroll
        for (int kk = 0; kk < 2; kk++) {
#pragma unroll
            for (int nt = 0; nt < 4; nt++) {
                int row = nt*16 + c;
                short8 vf = *(const short8*)(&Vs[row*64 + (((kk*4+qd) ^ (row&7))*8)]);
                oacc[nt] = mfma16(pf[kk], vf, oacc[nt]);
            }
        }
    }

    int b = bh >> 4, h = bh & (NH-1);
#pragma unroll
    for (int nt = 0; nt < 4; nt++) {
        int d = h*HD + nt*16 + c;
#pragma unroll
        for (int r = 0; r < 4; r++) {
            int s = iwave + qd*4 + r;
            attn[((size_t)(b*SEQ + s))*DM + d] = f2b(oacc[nt][r]);
        }
    }
}

// ---------------- GroupNorm stats: two-stage reduction ----------------
__global__ __launch_bounds__(256) void gn_partial(
    const float* __restrict__ proj, float* __restrict__ partials)
{
    int bg = blockIdx.x;              // 0..31 : (b,g)
    int chunk = blockIdx.y;           // 0..15 : seq chunk of 128 rows
    int b = bg >> 4, g = bg & (NH-1);
    const float* base = proj + (size_t)b*SEQ*DM + g*HD;
    int tid = threadIdx.x;
    int rlane = tid & 15;
    int rrow  = tid >> 4;
    float s = 0.f, ss = 0.f;
#pragma unroll
    for (int it = 0; it < 8; it++) {
        int srow = chunk*128 + it*16 + rrow;
        f32x4 v = *(const f32x4*)(base + (size_t)srow*DM + rlane*4);
        s  += v[0] + v[1] + v[2] + v[3];
        ss += v[0]*v[0] + v[1]*v[1] + v[2]*v[2] + v[3]*v[3];
    }
#pragma unroll
    for (int off = 32; off > 0; off >>= 1) {
        s  += __shfl_down(s, off);
        ss += __shfl_down(ss, off);
    }
    __shared__ float red[8];
    int w = tid >> 6, l = tid & 63;
    if (l == 0) { red[w*2] = s; red[w*2+1] = ss; }
    __syncthreads();
    if (tid == 0) {
        float S  = red[0]+red[2]+red[4]+red[6];
        float SS = red[1]+red[3]+red[5]+red[7];
        partials[(bg*16 + chunk)*2]     = S;
        partials[(bg*16 + chunk)*2 + 1] = SS;
    }
}

__global__ __launch_bounds__(64) void gn_finalize(
    const float* __restrict__ partials, float* __restrict__ stats)
{
    int bg = blockIdx.x;
    int l = threadIdx.x;
    float s  = (l < 16) ? partials[(bg*16 + l)*2]     : 0.f;
    float ss = (l < 16) ? partials[(bg*16 + l)*2 + 1] : 0.f;
#pragma unroll
    for (int off = 8; off > 0; off >>= 1) {
        s  += __shfl_down(s, off);
        ss += __shfl_down(ss, off);
    }
    if (l == 0) {
        const float inv = 1.0f / (float)(SEQ*HD);
        float mu = s * inv;
        float var = ss * inv - mu*mu;
        stats[bg*2]   = mu;
        stats[bg*2+1] = rsqrtf(var + 1e-5f);
    }
}

__global__ __launch_bounds__(256) void gn_apply(
    const float* __restrict__ proj, const float* __restrict__ stats,
    const u16* __restrict__ gamma, const u16* __restrict__ beta,
    const int* __restrict__ flag, void* __restrict__ outv)
{
    int idx = blockIdx.x * 256 + threadIdx.x;
    int d = idx & (DM-1);
    int bs = idx >> 10;
    int b = bs >> 11;
    int g = d >> 6;
    float mu   = stats[(b*NH + g)*2];
    float rstd = stats[(b*NH + g)*2 + 1];
    float v = (proj[idx] - mu) * rstd * b2f(gamma[d]) + b2f(beta[d]);
    if (*flag) ((float*)outv)[idx] = v;
    else       ((u16*)outv)[idx]   = f2b(v);
}

// ---------------- launch ----------------
extern "C" void kernel_launch(void* const* d_in, const int* in_sizes, int n_in,
                              void* d_out, int out_size, void* d_ws, size_t ws_size,
                              hipStream_t stream) {
    const void* x     = d_in[0];
    const void* Wq    = d_in[1];
    const void* bq    = d_in[2];
    const void* Wk    = d_in[3];
    const void* bk    = d_in[4];
    const void* Wv    = d_in[5];
    const void* bv    = d_in[6];
    const void* Wo    = d_in[7];
    const void* bo    = d_in[8];
    const void* gamma = d_in[9];
    const void* beta  = d_in[10];

    const size_t MB = 1024*1024;
    char* ws = (char*)d_ws;
    int*   flag     = (int*)ws;
    u16*   bqc      = (u16*)(ws + 4096);
    u16*   bkc      = (u16*)(ws + 8192);
    u16*   bvc      = (u16*)(ws + 12288);
    u16*   boc      = (u16*)(ws + 16384);
    u16*   gammac   = (u16*)(ws + 20480);
    u16*   betac    = (u16*)(ws + 24576);
    float* stats    = (float*)(ws + 28672);
    float* partials = (float*)(ws + 32768);
    u16*   xc     = (u16*)(ws + 1*MB);
    u16*   WqT    = (u16*)(ws + 9*MB);
    u16*   WkT    = (u16*)(ws + 11*MB);
    u16*   WvT    = (u16*)(ws + 13*MB);
    u16*   WoT    = (u16*)(ws + 15*MB);
    u16*   qb     = (u16*)(ws + 17*MB);
    u16*   kb     = (u16*)(ws + 25*MB);
    u16*   vTb    = (u16*)(ws + 33*MB);
    u16*   attn   = (u16*)(ws + 41*MB);
    float* proj   = (float*)(ws + 17*MB); // overlays qb/kb (free after retention)

    detect_dtype<<<1, 64, 0, stream>>>((const u16*)Wq, flag);
    convert_x<<<4096, 256, 0, stream>>>(x, flag, xc);
    convert_small<<<6, 256, 0, stream>>>(bq, bk, bv, bo, gamma, beta, flag,
                                         bqc, bkc, bvc, boc, gammac, betac);
    transpose4<<<dim3(32, 32, 4), 256, 0, stream>>>(Wq, Wk, Wv, Wo, flag, WqT, WkT, WvT, WoT);
    gemm_qkv<<<dim3(32, 8, 3), 256, 0, stream>>>(xc, WqT, WkT, WvT, bqc, bkc, bvc, qb, kb, vTb);
    retention<<<dim3(32, 32), 256, 0, stream>>>(qb, kb, vTb, attn);
    gemm_out<<<dim3(32, 8), 256, 0, stream>>>(attn, WoT, boc, proj);
    gn_partial<<<dim3(32, 16), 256, 0, stream>>>(proj, partials);
    gn_finalize<<<32, 64, 0, stream>>>(partials, stats);
    gn_apply<<<(SEQ*DM*2)/256, 256, 0, stream>>>(proj, stats, gammac, betac, flag, d_out);
}

// Round 9
// 186.082 us; speedup vs baseline: 1.4879x; 1.0418x over previous
//
#include <hip/hip_runtime.h>
#include <hip/hip_bf16.h>

typedef unsigned short u16;
typedef __attribute__((ext_vector_type(8))) short short8;
typedef __attribute__((ext_vector_type(4))) float f32x4;
typedef __attribute__((ext_vector_type(4))) unsigned short u16x4;

#define SEQ 2048
#define NH 16
#define HD 64
#define DM 1024
#define LN_DECAY (-0.051293294387550536f)
// decay window: contributions beyond distance ~256 are < 1e-5 of output std
#define WIN_TILES 4

__device__ __forceinline__ float b2f(u16 u) {
    return __uint_as_float(((unsigned int)u) << 16);
}
__device__ __forceinline__ u16 f2b(float f) {
    unsigned int u = __float_as_uint(f);
    u += 0x7fffu + ((u >> 16) & 1u);   // round-to-nearest-even
    return (u16)(u >> 16);
}
__device__ __forceinline__ f32x4 mfma16(short8 a, short8 b, f32x4 c) {
    return __builtin_amdgcn_mfma_f32_16x16x32_bf16(a, b, c, 0, 0, 0);
}
// async global->LDS, 16B per lane; dest = wave-uniform base + lane*16
__device__ __forceinline__ void gld_lds16(const u16* g, u16* l) {
    __builtin_amdgcn_global_load_lds(
        (const __attribute__((address_space(1))) void*)g,
        (__attribute__((address_space(3))) void*)l, 16, 0, 0);
}
// wave-uniform dtype detect: 256 samples of Wq's even u16 words; fp32 low
// mantissa words have uniform "exponent" bits -> some sample >= 0xC0
// w.p. 1-0.75^256. bf16 N(0,1/32) weights never reach exp 0xC0.
__device__ __forceinline__ int detect_fl(const u16* Wq, int lane) {
    int hit = 0;
#pragma unroll
    for (int j = 0; j < 4; j++) {
        u16 u = Wq[2*(lane + 64*j)];
        if (((u >> 7) & 0xFF) >= 0xC0) hit = 1;
    }
    return (__ballot(hit) != 0ULL) ? 1 : 0;
}

// ---------------- prep: dtype detect + all conversions + transposes -------
// blocks [0,4096): convert x; block 4096: small tensors + flag + zero stats;
// blocks [4097, 8193): transpose 4 weight matrices (1024 tiles each).
__global__ __launch_bounds__(256) void prep(
    const void* __restrict__ x,
    const void* __restrict__ Wq, const void* __restrict__ Wk,
    const void* __restrict__ Wv, const void* __restrict__ Wo,
    const void* __restrict__ bq, const void* __restrict__ bk,
    const void* __restrict__ bv, const void* __restrict__ bo,
    const void* __restrict__ gamma, const void* __restrict__ beta,
    u16* __restrict__ xc,
    u16* __restrict__ WqT, u16* __restrict__ WkT,
    u16* __restrict__ WvT, u16* __restrict__ WoT,
    u16* __restrict__ bqc, u16* __restrict__ bkc, u16* __restrict__ bvc,
    u16* __restrict__ boc, u16* __restrict__ gammac, u16* __restrict__ betac,
    int* __restrict__ flag, float* __restrict__ statsAcc)
{
    __shared__ u16 tileS[32][33];
    int bid = blockIdx.x, tid = threadIdx.x;
    int fl = detect_fl((const u16*)Wq, tid & 63);

    if (bid < 4096) {
        int i = (bid*256 + tid)*4;
        if (fl) {
            f32x4 v = *(const f32x4*)((const float*)x + i);
            u16x4 o = { f2b(v[0]), f2b(v[1]), f2b(v[2]), f2b(v[3]) };
            *(u16x4*)(xc + i) = o;
        } else {
            *(u16x4*)(xc + i) = *(const u16x4*)((const u16*)x + i);
        }
    } else if (bid == 4096) {
        const void* ins[6] = {bq, bk, bv, bo, gamma, beta};
        u16* outs[6] = {bqc, bkc, bvc, boc, gammac, betac};
        int i = tid*4;
#pragma unroll
        for (int a = 0; a < 6; a++) {
            if (fl) {
                f32x4 v = *(const f32x4*)((const float*)ins[a] + i);
                u16x4 o = { f2b(v[0]), f2b(v[1]), f2b(v[2]), f2b(v[3]) };
                *(u16x4*)(outs[a] + i) = o;
            } else {
                *(u16x4*)(outs[a] + i) = *(const u16x4*)((const u16*)ins[a] + i);
            }
        }
        if (tid == 0) *flag = fl;
        if (tid < 64) statsAcc[tid] = 0.f;
    } else {
        int tb = bid - 4097;
        int wsel = tb >> 10, tile = tb & 1023;
        const void* W = (wsel==0) ? Wq : (wsel==1) ? Wk : (wsel==2) ? Wv : Wo;
        u16* T        = (wsel==0) ? WqT : (wsel==1) ? WkT : (wsel==2) ? WvT : WoT;
        int bn = (tile & 31)*32, bk_ = (tile >> 5)*32;
        int r = tid >> 5, c = tid & 31;
#pragma unroll
        for (int i2 = 0; i2 < 4; i2++) {
            size_t idx = (size_t)(bk_ + r + i2*8)*DM + bn + c;
            tileS[r + i2*8][c] = fl ? f2b(((const float*)W)[idx]) : ((const u16*)W)[idx];
        }
        __syncthreads();
#pragma unroll
        for (int i2 = 0; i2 < 4; i2++)
            T[(size_t)(bn + r + i2*8)*DM + bk_ + c] = tileS[c][r + i2*8];
    }
}

// ---------------- 128x128 MFMA GEMM body ----------------
// Packed LDS [128][32] (global_load_lds forbids padding). Source-side XOR
// swizzle: elem A[row][k0+c*8+e] lives at LDS[row*32 + (c ^ ((row>>1)&3))*8 + e]
// -> b128 frag reads alias only 2-way (free).
// MODE 0: out bf16 [bh][s][d]; MODE 2: out bf16 [bh][d][s] (v^T);
// MODE 3: out fp32 proj + per-wave GN stats atomics.
template<int MODE>
__device__ __forceinline__ void gemm_body(
    const u16* __restrict__ A, const u16* __restrict__ BT,
    const u16* __restrict__ bias, u16* __restrict__ outB,
    float* __restrict__ outF, float* __restrict__ stats,
    int m0, int n0, int t)
{
    __shared__ u16 As[128*32];
    __shared__ u16 Bs[128*32];
    int w = t >> 6, l = t & 63;
    int lane16 = l & 15, quad = l >> 4;
    int wm = (w >> 1) * 64, wn = (w & 1) * 64;

    int srow   = t >> 2;                      // 0..63 staging row
    int schunk = (t & 3) ^ ((t >> 3) & 3);    // swizzled source chunk

    f32x4 zero = {0.f, 0.f, 0.f, 0.f};
    f32x4 acc[4][4];
#pragma unroll
    for (int i = 0; i < 4; i++)
#pragma unroll
        for (int j = 0; j < 4; j++)
            acc[i][j] = zero;

    const u16* a0 = A  + (size_t)(m0 + srow)      * DM + schunk*8;
    const u16* a1 = A  + (size_t)(m0 + srow + 64) * DM + schunk*8;
    const u16* b0 = BT + (size_t)(n0 + srow)      * DM + schunk*8;
    const u16* b1 = BT + (size_t)(n0 + srow + 64) * DM + schunk*8;

    for (int k0 = 0; k0 < DM; k0 += 32) {
        __syncthreads();
        gld_lds16(a0 + k0, &As[t*8]);
        gld_lds16(a1 + k0, &As[2048 + t*8]);
        gld_lds16(b0 + k0, &Bs[t*8]);
        gld_lds16(b1 + k0, &Bs[2048 + t*8]);
        __syncthreads();
        short8 af[4], bf[4];
#pragma unroll
        for (int i = 0; i < 4; i++) {
            int ra = wm + i*16 + lane16;
            int rb = wn + i*16 + lane16;
            af[i] = *(const short8*)(&As[ra*32 + ((quad ^ ((ra>>1)&3))*8)]);
            bf[i] = *(const short8*)(&Bs[rb*32 + ((quad ^ ((rb>>1)&3))*8)]);
        }
#pragma unroll
        for (int i = 0; i < 4; i++)
#pragma unroll
            for (int j = 0; j < 4; j++)
                acc[i][j] = mfma16(af[i], bf[j], acc[i][j]);
    }

    float s = 0.f, ss = 0.f;
#pragma unroll
    for (int i = 0; i < 4; i++) {
#pragma unroll
        for (int j = 0; j < 4; j++) {
            int n = n0 + wn + j*16 + lane16;
            float bv = b2f(bias[n]);
#pragma unroll
            for (int r = 0; r < 4; r++) {
                int m = m0 + wm + i*16 + quad*4 + r;
                float v = acc[i][j][r] + bv;
                if (MODE == 3) {
                    outF[(size_t)m*DM + n] = v;
                    s += v; ss += v*v;
                } else {
                    int b = m >> 11, sq = m & (SEQ-1);
                    int h = n >> 6,  d = n & (HD-1);
                    if (MODE == 2)
                        outB[(((size_t)(b*NH + h))*HD + d)*SEQ + sq] = f2b(v);
                    else
                        outB[(((size_t)(b*NH + h))*SEQ + sq)*HD + d] = f2b(v);
                }
            }
        }
    }
    if (MODE == 3) {
        // all 64 values of this wave lie in one (b, group): g=(n0+wn)>>6
#pragma unroll
        for (int off = 32; off > 0; off >>= 1) {
            s  += __shfl_down(s, off);
            ss += __shfl_down(ss, off);
        }
        if (l == 0) {
            int b = m0 >> 11;
            int g = (n0 + wn) >> 6;
            atomicAdd(&stats[(b*NH + g)*2],     s);
            atomicAdd(&stats[(b*NH + g)*2 + 1], ss);
        }
    }
}

__global__ __launch_bounds__(256) void gemm_qkv(
    const u16* __restrict__ x,
    const u16* __restrict__ WqT, const u16* __restrict__ WkT, const u16* __restrict__ WvT,
    const u16* __restrict__ bq, const u16* __restrict__ bk, const u16* __restrict__ bv,
    u16* __restrict__ qb, u16* __restrict__ kb, u16* __restrict__ vTb)
{
    int z = blockIdx.z;
    const u16* BT   = (z==0) ? WqT : (z==1) ? WkT : WvT;
    const u16* bias = (z==0) ? bq  : (z==1) ? bk  : bv;
    u16* outB       = (z==0) ? qb  : (z==1) ? kb  : vTb;
    if (z == 2)
        gemm_body<2>(x, BT, bias, outB, nullptr, nullptr,
                     blockIdx.x * 128, blockIdx.y * 128, threadIdx.x);
    else
        gemm_body<0>(x, BT, bias, outB, nullptr, nullptr,
                     blockIdx.x * 128, blockIdx.y * 128, threadIdx.x);
}

__global__ __launch_bounds__(256) void gemm_out(
    const u16* __restrict__ attn, const u16* __restrict__ WoT,
    const u16* __restrict__ bo, float* __restrict__ proj,
    float* __restrict__ statsAcc)
{
    gemm_body<3>(attn, WoT, bo, nullptr, proj, statsAcc,
                 blockIdx.x * 128, blockIdx.y * 128, threadIdx.x);
}

// ---------------- retention: out = (QK^T * decay_mask) @ V ----------------
// Sliding-window: decay^d < 2e-6 for d > 256, so each 64-row q-tile only
// processes j-tiles [qt-WIN_TILES, qt]. Grid 32x32 = 1024 blocks (4/CU).
// LDS XOR swizzle: elem(row,col) at row*64 + ((col>>3 ^ (row&7))*8) + (col&7)
__global__ __launch_bounds__(256) void retention(
    const u16* __restrict__ q, const u16* __restrict__ k,
    const u16* __restrict__ vT, u16* __restrict__ attn)
{
    __shared__ u16 Ks[64*64];
    __shared__ u16 Vs[64*64];
    __shared__ u16 Ps[4][16*64];   // per-wave P tile

    int qt = blockIdx.x, bh = blockIdx.y;
    int t = threadIdx.x, w = t >> 6, l = t & 63;
    int c = l & 15, qd = l >> 4;
    int qbase = qt * 64;
    int iwave = qbase + w*16;

    const u16* qh = q  + (size_t)bh * SEQ * HD;
    const u16* kh = k  + (size_t)bh * SEQ * HD;
    const u16* vh = vT + (size_t)bh * HD * SEQ;

    // decay tables: wgt(i,j) = base(iter) * D[r] * E[st]
    float D[4], E[4];
#pragma unroll
    for (int r = 0; r < 4; r++)
        D[r] = __expf((float)(qd*4 + r) * LN_DECAY);
#pragma unroll
    for (int st = 0; st < 4; st++)
        E[st] = __expf(-(float)(st*16 + c) * LN_DECAY);

    int sr = t >> 3, sc8 = t & 7;

    short8 qf[2];
#pragma unroll
    for (int kk = 0; kk < 2; kk++)
        qf[kk] = *(const short8*)(qh + (size_t)(iwave + c)*HD + kk*32 + qd*8);

    f32x4 zero = {0.f, 0.f, 0.f, 0.f};
    f32x4 oacc[4] = {zero, zero, zero, zero};

    int jt0 = (qt > WIN_TILES) ? (qt - WIN_TILES) : 0;
#pragma unroll 1
    for (int jt = jt0; jt <= qt; jt++) {
        int jbase = jt * 64;
        __syncthreads();
        {
            int r0 = sr, r1 = sr + 32;
            *(short8*)(&Ks[r0*64 + ((sc8 ^ (r0&7))*8)]) = *(const short8*)(kh + (size_t)(jbase+r0)*HD + sc8*8);
            *(short8*)(&Ks[r1*64 + ((sc8 ^ (r1&7))*8)]) = *(const short8*)(kh + (size_t)(jbase+r1)*HD + sc8*8);
            *(short8*)(&Vs[r0*64 + ((sc8 ^ (r0&7))*8)]) = *(const short8*)(vh + (size_t)r0*SEQ + jbase + sc8*8);
            *(short8*)(&Vs[r1*64 + ((sc8 ^ (r1&7))*8)]) = *(const short8*)(vh + (size_t)(r1)*SEQ + jbase + sc8*8);
        }
        __syncthreads();

        // S = q @ k^T   (C layout: row=i=qd*4+r, col=j=c)
        f32x4 sacc[4] = {zero, zero, zero, zero};
#pragma unroll
        for (int kk = 0; kk < 2; kk++) {
#pragma unroll
            for (int st = 0; st < 4; st++) {
                int row = st*16 + c;
                short8 bf = *(const short8*)(&Ks[row*64 + (((kk*4+qd) ^ (row&7))*8)]);
                sacc[st] = mfma16(qf[kk], bf, sacc[st]);
            }
        }

        float base = __expf((float)(iwave - jbase) * LN_DECAY);
#pragma unroll
        for (int st = 0; st < 4; st++) {
            int j = jbase + st*16 + c;
            float bE = base * E[st];
#pragma unroll
            for (int r = 0; r < 4; r++) {
                int i = iwave + qd*4 + r;
                float val = (i >= j) ? sacc[st][r] * (bE * D[r]) : 0.0f;
                int row = qd*4 + r;
                int col = st*16 + c;
                Ps[w][row*64 + (((col>>3) ^ (row&7))*8) + (col&7)] = f2b(val);
            }
        }
        asm volatile("s_waitcnt lgkmcnt(0)" ::: "memory");
        short8 pf[2];
#pragma unroll
        for (int kk = 0; kk < 2; kk++)
            pf[kk] = *(const short8*)(&Ps[w][c*64 + (((kk*4+qd) ^ (c&7))*8)]);

        // O += P @ V
#pragma unroll
        for (int kk = 0; kk < 2; kk++) {
#pragma unroll
            for (int nt = 0; nt < 4; nt++) {
                int row = nt*16 + c;
                short8 vf = *(const short8*)(&Vs[row*64 + (((kk*4+qd) ^ (row&7))*8)]);
                oacc[nt] = mfma16(pf[kk], vf, oacc[nt]);
            }
        }
    }

    int b = bh >> 4, h = bh & (NH-1);
#pragma unroll
    for (int nt = 0; nt < 4; nt++) {
        int d = h*HD + nt*16 + c;
#pragma unroll
        for (int r = 0; r < 4; r++) {
            int s = iwave + qd*4 + r;
            attn[((size_t)(b*SEQ + s))*DM + d] = f2b(oacc[nt][r]);
        }
    }
}

// ---------------- GroupNorm apply (stats folded inline) ----------------
__global__ __launch_bounds__(256) void gn_apply(
    const float* __restrict__ proj, const float* __restrict__ statsAcc,
    const u16* __restrict__ gamma, const u16* __restrict__ beta,
    const int* __restrict__ flag, void* __restrict__ outv)
{
    int base = (blockIdx.x*256 + threadIdx.x)*4;
    int d = base & (DM-1);
    int b = base >> 21;         // batch stride = SEQ*DM = 2^21
    int g = d >> 6;
    float S  = statsAcc[(b*NH + g)*2];
    float SS = statsAcc[(b*NH + g)*2 + 1];
    const float inv = 1.0f/(float)(SEQ*HD);
    float mu = S*inv;
    float rstd = rsqrtf(SS*inv - mu*mu + 1e-5f);
    f32x4 v = *(const f32x4*)(proj + base);
    float o0 = (v[0]-mu)*rstd*b2f(gamma[d])   + b2f(beta[d]);
    float o1 = (v[1]-mu)*rstd*b2f(gamma[d+1]) + b2f(beta[d+1]);
    float o2 = (v[2]-mu)*rstd*b2f(gamma[d+2]) + b2f(beta[d+2]);
    float o3 = (v[3]-mu)*rstd*b2f(gamma[d+3]) + b2f(beta[d+3]);
    if (*flag) {
        f32x4 ov = {o0, o1, o2, o3};
        *(f32x4*)((float*)outv + base) = ov;
    } else {
        u16x4 ov = {f2b(o0), f2b(o1), f2b(o2), f2b(o3)};
        *(u16x4*)((u16*)outv + base) = ov;
    }
}

// ---------------- launch ----------------
extern "C" void kernel_launch(void* const* d_in, const int* in_sizes, int n_in,
                              void* d_out, int out_size, void* d_ws, size_t ws_size,
                              hipStream_t stream) {
    const void* x     = d_in[0];
    const void* Wq    = d_in[1];
    const void* bq    = d_in[2];
    const void* Wk    = d_in[3];
    const void* bk    = d_in[4];
    const void* Wv    = d_in[5];
    const void* bv    = d_in[6];
    const void* Wo    = d_in[7];
    const void* bo    = d_in[8];
    const void* gamma = d_in[9];
    const void* beta  = d_in[10];

    const size_t MB = 1024*1024;
    char* ws = (char*)d_ws;
    int*   flag     = (int*)ws;
    u16*   bqc      = (u16*)(ws + 4096);
    u16*   bkc      = (u16*)(ws + 8192);
    u16*   bvc      = (u16*)(ws + 12288);
    u16*   boc      = (u16*)(ws + 16384);
    u16*   gammac   = (u16*)(ws + 20480);
    u16*   betac    = (u16*)(ws + 24576);
    float* statsAcc = (float*)(ws + 28672);
    u16*   xc     = (u16*)(ws + 1*MB);
    u16*   WqT    = (u16*)(ws + 9*MB);
    u16*   WkT    = (u16*)(ws + 11*MB);
    u16*   WvT    = (u16*)(ws + 13*MB);
    u16*   WoT    = (u16*)(ws + 15*MB);
    u16*   qb     = (u16*)(ws + 17*MB);
    u16*   kb     = (u16*)(ws + 25*MB);
    u16*   vTb    = (u16*)(ws + 33*MB);
    u16*   attn   = (u16*)(ws + 41*MB);
    float* proj   = (float*)(ws + 17*MB); // overlays qb/kb (free after retention)

    prep<<<8193, 256, 0, stream>>>(x, Wq, Wk, Wv, Wo, bq, bk, bv, bo, gamma, beta,
                                   xc, WqT, WkT, WvT, WoT,
                                   bqc, bkc, bvc, boc, gammac, betac,
                                   flag, statsAcc);
    gemm_qkv<<<dim3(32, 8, 3), 256, 0, stream>>>(xc, WqT, WkT, WvT, bqc, bkc, bvc, qb, kb, vTb);
    retention<<<dim3(32, 32), 256, 0, stream>>>(qb, kb, vTb, attn);
    gemm_out<<<dim3(32, 8), 256, 0, stream>>>(attn, WoT, boc, proj, statsAcc);
    gn_apply<<<4096, 256, 0, stream>>>(proj, statsAcc, gammac, betac, flag, d_out);
}